// Round 1
// baseline (3126.793 us; speedup 1.0000x reference)
//
#include <hip/hip_runtime.h>
#include <math.h>

#define NN 50000
#define EE 800000
#define RR 8
#define BB 4
#define SLOPE 0.2f

__device__ __forceinline__ float leaky(float v) { return v >= 0.f ? v : SLOPE * v; }

__device__ __forceinline__ void atomicMaxF(float* addr, float val) {
    int* ai = (int*)addr;
    int old = *ai;
    while (__int_as_float(old) < val) {
        int assumed = old;
        old = atomicCAS(ai, assumed, __float_as_int(val));
        if (old == assumed) break;
    }
}

// ---------------- weights: W_r = sum_b comp[r,b] * basis[b] ----------------
__global__ void k_weights(const float* __restrict__ basis1, const float* __restrict__ comp1,
                          const float* __restrict__ basis2, const float* __restrict__ comp2,
                          float* __restrict__ W1, float* __restrict__ W2) {
    int idx = blockIdx.x * 256 + threadIdx.x;
    if (idx < RR * 64 * 64) {
        int r = idx >> 12, io = idx & 4095;
        float acc = 0.f;
        for (int b = 0; b < BB; b++) acc += comp1[r * BB + b] * basis1[b * 4096 + io];
        W1[idx] = acc;
    } else if (idx < 2 * RR * 64 * 64) {
        int j = idx - RR * 64 * 64;
        int r = j >> 12, io = j & 4095;
        float acc = 0.f;
        for (int b = 0; b < BB; b++) acc += comp2[r * BB + b] * basis2[b * 4096 + io];
        W2[j] = acc;
    }
}

__global__ void k_init_m(float* __restrict__ m1, float* __restrict__ m2) {
    int i = blockIdx.x * 256 + threadIdx.x;
    if (i < NN * 4) { m1[i] = -1e30f; m2[i] = -1e30f; }
}

__global__ void k_count(const int* __restrict__ dst, const int* __restrict__ et,
                        float* __restrict__ cnt) {
    int e = blockIdx.x * 256 + threadIdx.x;
    if (e < EE) atomicAdd(cnt + dst[e] * RR + et[e], 1.f);
}

// ------------- RGCN1 edge scatter: 64 lanes per edge, in=64 out=64 -------------
__global__ void k_rgcn1(const float* __restrict__ x, const int* __restrict__ src,
                        const int* __restrict__ dst, const int* __restrict__ et,
                        const float* __restrict__ W1, const float* __restrict__ cnt,
                        float* __restrict__ out) {
    int tid = blockIdx.x * 256 + threadIdx.x;
    int e = tid >> 6, o = tid & 63;
    if (e >= EE) return;
    int s = src[e], d = dst[e], r = et[e];
    const float* xs = x + s * 64;
    const float* w = W1 + r * 4096 + o;
    float acc = 0.f;
#pragma unroll
    for (int i = 0; i < 64; i++) acc += xs[i] * w[i * 64];
    atomicAdd(out + d * 64 + o, acc / cnt[d * RR + r]);
}

__global__ void k_root1(const float* __restrict__ x, const float* __restrict__ root,
                        const float* __restrict__ bias, float* __restrict__ x1) {
    int tid = blockIdx.x * 256 + threadIdx.x;
    int n = tid >> 6, o = tid & 63;
    if (n >= NN) return;
    const float* xs = x + n * 64;
    float acc = bias[o];
#pragma unroll
    for (int i = 0; i < 64; i++) acc += xs[i] * root[i * 64 + o];
    float v = x1[n * 64 + o] + acc;
    x1[n * 64 + o] = v > 0.f ? v : 0.f;
}

// ------------- GAT1: h = x1 @ wg1 (64 -> 128) -------------
__global__ void k_gat1_h(const float* __restrict__ x1, const float* __restrict__ wg,
                         float* __restrict__ h) {
    int tid = blockIdx.x * 256 + threadIdx.x;
    int n = tid >> 7, o = tid & 127;
    if (n >= NN) return;
    const float* xs = x1 + n * 64;
    float acc = 0.f;
#pragma unroll
    for (int i = 0; i < 64; i++) acc += xs[i] * wg[i * 128 + o];
    h[n * 128 + o] = acc;
}

// per (n, head): al_src / al_dst reductions over C channels
__global__ void k_gat_al(const float* __restrict__ h, const float* __restrict__ a_src,
                         const float* __restrict__ a_dst, float* __restrict__ als,
                         float* __restrict__ ald, int C) {
    int i = blockIdx.x * 256 + threadIdx.x;  // i = n*4 + hh
    if (i >= NN * 4) return;
    int hh = i & 3;
    const float* hp = h + i * C;  // (n*4+hh)*C == n*(4C) + hh*C
    float a = 0.f, b = 0.f;
    for (int c = 0; c < C; c++) { float v = hp[c]; a += v * a_src[hh * C + c]; b += v * a_dst[hh * C + c]; }
    als[i] = a; ald[i] = b;
}

__global__ void k_gat_max(const int* __restrict__ src, const int* __restrict__ dst,
                          const float* __restrict__ als, const float* __restrict__ ald,
                          float* __restrict__ m) {
    int e = blockIdx.x * 256 + threadIdx.x;
    if (e >= EE + NN) return;
    int s, d;
    if (e < EE) { s = src[e]; d = dst[e]; } else { s = d = e - EE; }
#pragma unroll
    for (int hh = 0; hh < 4; hh++) {
        float v = leaky(als[s * 4 + hh] + ald[d * 4 + hh]);
        atomicMaxF(m + d * 4 + hh, v);
    }
}

__global__ void k_gat_z(const int* __restrict__ src, const int* __restrict__ dst,
                        const float* __restrict__ als, const float* __restrict__ ald,
                        const float* __restrict__ m, float* __restrict__ z) {
    int e = blockIdx.x * 256 + threadIdx.x;
    if (e >= EE + NN) return;
    int s, d;
    if (e < EE) { s = src[e]; d = dst[e]; } else { s = d = e - EE; }
#pragma unroll
    for (int hh = 0; hh < 4; hh++) {
        float v = leaky(als[s * 4 + hh] + ald[d * 4 + hh]);
        atomicAdd(z + d * 4 + hh, expf(v - m[d * 4 + hh]));
    }
}

// HC = heads*C channels per node; one thread per (edge, channel)
template <int HC, int C>
__global__ void k_gat_scatter(const int* __restrict__ src, const int* __restrict__ dst,
                              const float* __restrict__ als, const float* __restrict__ ald,
                              const float* __restrict__ m, const float* __restrict__ z,
                              const float* __restrict__ h, float* __restrict__ out) {
    int tid = blockIdx.x * 256 + threadIdx.x;
    int e = tid / HC, j = tid % HC;
    if (e >= EE + NN) return;
    int s, d;
    if (e < EE) { s = src[e]; d = dst[e]; } else { s = d = e - EE; }
    int hh = j / C;
    float v = leaky(als[s * 4 + hh] + ald[d * 4 + hh]);
    float alpha = expf(v - m[d * 4 + hh]) / z[d * 4 + hh];
    atomicAdd(out + d * HC + j, alpha * h[s * HC + j]);
}

__global__ void k_bias128(const float* __restrict__ bg, float* __restrict__ x2) {
    int tid = blockIdx.x * 256 + threadIdx.x;
    int n = tid >> 7, j = tid & 127;
    if (n >= NN) return;
    x2[n * 128 + j] += bg[j];
}

// ------------- RGCN2 edge scatter: 32 lanes per edge, in=128 out=32 -------------
__global__ void k_rgcn2(const float* __restrict__ x2, const int* __restrict__ src,
                        const int* __restrict__ dst, const int* __restrict__ et,
                        const float* __restrict__ W2, const float* __restrict__ cnt,
                        float* __restrict__ out) {
    int tid = blockIdx.x * 256 + threadIdx.x;
    int e = tid >> 5, c = tid & 31;
    if (e >= EE) return;
    int s = src[e], d = dst[e], r = et[e];
    const float* xs = x2 + s * 128;
    const float* w = W2 + r * 4096 + c;
    float acc = 0.f;
#pragma unroll
    for (int i = 0; i < 128; i++) acc += xs[i] * w[i * 32];
    atomicAdd(out + d * 32 + c, acc / cnt[d * RR + r]);
}

__global__ void k_root2(const float* __restrict__ x2, const float* __restrict__ root,
                        const float* __restrict__ bias, float* __restrict__ x3) {
    int tid = blockIdx.x * 256 + threadIdx.x;
    int n = tid >> 5, c = tid & 31;
    if (n >= NN) return;
    const float* xs = x2 + n * 128;
    float acc = bias[c];
#pragma unroll
    for (int i = 0; i < 128; i++) acc += xs[i] * root[i * 32 + c];
    float v = x3[n * 32 + c] + acc;
    x3[n * 32 + c] = v > 0.f ? v : 0.f;
}

// ------------- GAT2: h = x3 @ wg2 (32 -> 64) -------------
__global__ void k_gat2_h(const float* __restrict__ x3, const float* __restrict__ wg,
                         float* __restrict__ h) {
    int tid = blockIdx.x * 256 + threadIdx.x;
    int n = tid >> 6, o = tid & 63;
    if (n >= NN) return;
    const float* xs = x3 + n * 32;
    float acc = 0.f;
#pragma unroll
    for (int i = 0; i < 32; i++) acc += xs[i] * wg[i * 64 + o];
    h[n * 64 + o] = acc;
}

__global__ void k_final(const float* __restrict__ acc2, const float* __restrict__ bg2,
                        float* __restrict__ out) {
    int tid = blockIdx.x * 256 + threadIdx.x;
    int n = tid >> 4, c = tid & 15;
    if (n >= NN) return;
    float v = 0.25f * (acc2[n * 64 + c] + acc2[n * 64 + 16 + c] +
                       acc2[n * 64 + 32 + c] + acc2[n * 64 + 48 + c]) + bg2[c];
    v = v > 0.f ? v : 0.f;
    out[n * 16 + c] = tanhf(v);
}

extern "C" void kernel_launch(void* const* d_in, const int* in_sizes, int n_in,
                              void* d_out, int out_size, void* d_ws, size_t ws_size,
                              hipStream_t stream) {
    const float* x      = (const float*)d_in[0];
    const int*   ei     = (const int*)d_in[1];
    const int*   et     = (const int*)d_in[2];
    const float* basis1 = (const float*)d_in[3];
    const float* comp1  = (const float*)d_in[4];
    const float* root1  = (const float*)d_in[5];
    const float* brg1   = (const float*)d_in[6];
    const float* wg1    = (const float*)d_in[7];
    const float* asrc1  = (const float*)d_in[8];
    const float* adst1  = (const float*)d_in[9];
    const float* bg1    = (const float*)d_in[10];
    const float* basis2 = (const float*)d_in[11];
    const float* comp2  = (const float*)d_in[12];
    const float* root2  = (const float*)d_in[13];
    const float* brg2   = (const float*)d_in[14];
    const float* wg2    = (const float*)d_in[15];
    const float* asrc2  = (const float*)d_in[16];
    const float* adst2  = (const float*)d_in[17];
    const float* bg2    = (const float*)d_in[18];
    const int* src = ei;
    const int* dst = ei + EE;
    float* out = (float*)d_out;

    // ---- workspace layout: zero-init accumulators first (single memset) ----
    float* ws = (float*)d_ws;
    size_t off = 0;
    auto alloc = [&](size_t n) { float* p = ws + off; off += n; return p; };
    // zeroed region:
    float* cnt  = alloc((size_t)NN * RR);    // 400000
    float* x1   = alloc((size_t)NN * 64);    // RGCN1 out accumulator
    float* x2   = alloc((size_t)NN * 128);   // GAT1 out accumulator
    float* x3   = alloc((size_t)NN * 32);    // RGCN2 out accumulator
    float* z1   = alloc((size_t)NN * 4);
    float* z2   = alloc((size_t)NN * 4);
    float* acc2 = alloc((size_t)NN * 64);    // GAT2 out accumulator (H*C=64)
    size_t zero_floats = off;
    // written-before-read region:
    float* W1   = alloc(RR * 64 * 64);
    float* W2   = alloc(RR * 128 * 32);
    float* h1   = alloc((size_t)NN * 128);
    float* als1 = alloc((size_t)NN * 4);
    float* ald1 = alloc((size_t)NN * 4);
    float* m1   = alloc((size_t)NN * 4);
    float* h2   = alloc((size_t)NN * 64);
    float* als2 = alloc((size_t)NN * 4);
    float* ald2 = alloc((size_t)NN * 4);
    float* m2   = alloc((size_t)NN * 4);
    if (ws_size < off * sizeof(float)) return;  // workspace too small: bail (fails loudly)

    hipMemsetAsync(d_ws, 0, zero_floats * sizeof(float), stream);
    k_init_m<<<(NN * 4 + 255) / 256, 256, 0, stream>>>(m1, m2);
    k_weights<<<(2 * RR * 64 * 64) / 256, 256, 0, stream>>>(basis1, comp1, basis2, comp2, W1, W2);
    k_count<<<(EE + 255) / 256, 256, 0, stream>>>(dst, et, cnt);

    // ---- layer 1: RGCN(64->64) + relu ----
    k_rgcn1<<<EE * 64 / 256, 256, 0, stream>>>(x, src, dst, et, W1, cnt, x1);
    k_root1<<<NN * 64 / 256, 256, 0, stream>>>(x, root1, brg1, x1);

    // ---- layer 2: GAT(64 -> 4x32, concat) ----
    k_gat1_h<<<NN * 128 / 256, 256, 0, stream>>>(x1, wg1, h1);
    k_gat_al<<<(NN * 4 + 255) / 256, 256, 0, stream>>>(h1, asrc1, adst1, als1, ald1, 32);
    k_gat_max<<<(EE + NN + 255) / 256, 256, 0, stream>>>(src, dst, als1, ald1, m1);
    k_gat_z<<<(EE + NN + 255) / 256, 256, 0, stream>>>(src, dst, als1, ald1, m1, z1);
    k_gat_scatter<128, 32><<<(size_t)(EE + NN) * 128 / 256, 256, 0, stream>>>(
        src, dst, als1, ald1, m1, z1, h1, x2);
    k_bias128<<<NN * 128 / 256, 256, 0, stream>>>(bg1, x2);

    // ---- layer 3: RGCN(128->32) + relu ----
    k_rgcn2<<<EE * 32 / 256, 256, 0, stream>>>(x2, src, dst, et, W2, cnt, x3);
    k_root2<<<NN * 32 / 256, 256, 0, stream>>>(x2, root2, brg2, x3);

    // ---- layer 4: GAT(32 -> 4x16, mean) + relu + tanh ----
    k_gat2_h<<<NN * 64 / 256, 256, 0, stream>>>(x3, wg2, h2);
    k_gat_al<<<(NN * 4 + 255) / 256, 256, 0, stream>>>(h2, asrc2, adst2, als2, ald2, 16);
    k_gat_max<<<(EE + NN + 255) / 256, 256, 0, stream>>>(src, dst, als2, ald2, m2);
    k_gat_z<<<(EE + NN + 255) / 256, 256, 0, stream>>>(src, dst, als2, ald2, m2, z2);
    k_gat_scatter<64, 16><<<(size_t)(EE + NN) * 64 / 256, 256, 0, stream>>>(
        src, dst, als2, ald2, m2, z2, h2, acc2);
    k_final<<<NN * 16 / 256, 256, 0, stream>>>(acc2, bg2, out);
}

// Round 2
// 1482.884 us; speedup vs baseline: 2.1086x; 2.1086x over previous
//
#include <hip/hip_runtime.h>
#include <math.h>

#define NN 50000
#define EE 800000
#define RR 8
#define SLOPE 0.2f
#define SEGS (NN * RR)            /* 400000 per-(node,relation) segments */
#define NBLK ((SEGS + 255) / 256) /* 1563 scan blocks */

__device__ __forceinline__ float leaky(float v) { return v >= 0.f ? v : SLOPE * v; }

// ============================ CSR build ============================
__global__ void k_count2(const int* __restrict__ dst, const int* __restrict__ et,
                         int* __restrict__ cnt2) {
    int e = blockIdx.x * 256 + threadIdx.x;
    if (e < EE) atomicAdd(&cnt2[dst[e] * RR + et[e]], 1);
}

// per-block exclusive scan; block sums out
__global__ void k_scanA(const int* __restrict__ cnt2, int* __restrict__ rp,
                        int* __restrict__ bsum) {
    __shared__ int sh[256];
    int t = threadIdx.x;
    int i = blockIdx.x * 256 + t;
    int v = (i < SEGS) ? cnt2[i] : 0;
    sh[t] = v;
    __syncthreads();
    for (int off = 1; off < 256; off <<= 1) {
        int u = (t >= off) ? sh[t - off] : 0;
        __syncthreads();
        sh[t] += u;
        __syncthreads();
    }
    if (i < SEGS) rp[i] = sh[t] - v;  // exclusive within block
    if (t == 255) bsum[blockIdx.x] = sh[255];
}

// single block: exclusive scan of NBLK block sums
__global__ void k_scanB(int* __restrict__ bsum) {
    __shared__ int sh[256];
    int t = threadIdx.x;
    int loc[8];
    int s = 0;
#pragma unroll
    for (int i = 0; i < 8; i++) {
        int idx = t * 8 + i;
        int v = (idx < NBLK) ? bsum[idx] : 0;
        loc[i] = v;
        s += v;
    }
    sh[t] = s;
    __syncthreads();
    for (int off = 1; off < 256; off <<= 1) {
        int u = (t >= off) ? sh[t - off] : 0;
        __syncthreads();
        sh[t] += u;
        __syncthreads();
    }
    int run = sh[t] - s;
#pragma unroll
    for (int i = 0; i < 8; i++) {
        int idx = t * 8 + i;
        if (idx < NBLK) {
            int v = loc[i];
            bsum[idx] = run;
            run += v;
        }
    }
}

__global__ void k_scanC(int* __restrict__ rp, const int* __restrict__ bsum,
                        int* __restrict__ wo) {
    int i = blockIdx.x * 256 + threadIdx.x;
    if (i < SEGS) {
        int v = rp[i] + bsum[blockIdx.x];
        rp[i] = v;
        wo[i] = v;
    }
    if (i == 0) rp[SEGS] = EE;
}

__global__ void k_fill(const int* __restrict__ src, const int* __restrict__ dst,
                       const int* __restrict__ et, int* __restrict__ wo,
                       int* __restrict__ srcs) {
    int e = blockIdx.x * 256 + threadIdx.x;
    if (e >= EE) return;
    int seg = dst[e] * RR + et[e];
    int pos = atomicAdd(&wo[seg], 1);
    srcs[pos] = src[e];
}

// ===================== RGCN segment-mean gather =====================
// one wave per dst node, lane = channel; relation r only
template <int IN>
__global__ void k_gather(const int* __restrict__ rp, const int* __restrict__ srcs,
                         const float* __restrict__ X, int r, float* __restrict__ mean) {
    int wid = threadIdx.x >> 6, lane = threadIdx.x & 63;
    int n = blockIdx.x * 4 + wid;
    if (n >= NN) return;
    int beg = rp[n * RR + r], end = rp[n * RR + r + 1];
    float a0 = 0.f, a1 = 0.f;
    for (int k = beg; k < end; k++) {
        int s = srcs[k];
        a0 += X[s * IN + lane];
        if (IN == 128) a1 += X[s * IN + 64 + lane];
    }
    int c = end - beg;
    float inv = 1.f / (float)(c > 0 ? c : 1);
    mean[n * IN + lane] = a0 * inv;
    if (IN == 128) mean[n * IN + 64 + lane] = a1 * inv;
}

// ===================== generic LDS-B GEMM =====================
// C[NN,KOUT] (+)= A[NN,K] @ B[K,KOUT]  (+bias)(relu)
// B either Bsrc directly, or basis-composed W_r = sum_b comp[r,b]*basis[b,:,:]
template <int K, int KOUT>
__global__ void k_gemm(const float* __restrict__ A, const float* __restrict__ Bsrc,
                       const float* __restrict__ basis, const float* __restrict__ comp,
                       int r, const float* __restrict__ bias, float* __restrict__ C,
                       int accum, int relu) {
    __shared__ float Bs[K * KOUT];
    int t = threadIdx.x;
    for (int i = t; i < K * KOUT; i += 256) {
        float v;
        if (basis) {
            v = 0.f;
#pragma unroll
            for (int b = 0; b < 4; b++) v += comp[r * 4 + b] * basis[b * K * KOUT + i];
        } else {
            v = Bsrc[i];
        }
        Bs[i] = v;
    }
    __syncthreads();
    int stride = gridDim.x * 256;
    for (int idx = blockIdx.x * 256 + t; idx < NN * KOUT; idx += stride) {
        int n = idx / KOUT, o = idx % KOUT;  // KOUT is power of 2
        const float* An = A + (size_t)n * K;
        float acc = 0.f;
#pragma unroll
        for (int k = 0; k < K; k++) acc += An[k] * Bs[k * KOUT + o];
        float v = acc;
        if (bias) v += bias[o];
        if (accum) v += C[idx];
        if (relu) v = fmaxf(v, 0.f);
        C[idx] = v;
    }
}

// ===================== attention logits =====================
__global__ void k_gat_al(const float* __restrict__ h, const float* __restrict__ a_src,
                         const float* __restrict__ a_dst, float* __restrict__ als,
                         float* __restrict__ ald, int C) {
    int i = blockIdx.x * 256 + threadIdx.x;  // i = n*4 + hh
    if (i >= NN * 4) return;
    int hh = i & 3;
    const float* hp = h + (size_t)i * C;
    float a = 0.f, b = 0.f;
    for (int c = 0; c < C; c++) {
        float v = hp[c];
        a += v * a_src[hh * C + c];
        b += v * a_dst[hh * C + c];
    }
    als[i] = a;
    ald[i] = b;
}

// ===================== fused per-dst GAT =====================
// one wave per dst node; lane owns channel(s); 2 passes over edge list; self loop inline
template <int HC, int C, bool MEANOUT>
__global__ void k_gat(const int* __restrict__ rp, const int* __restrict__ srcs,
                      const float* __restrict__ als, const float* __restrict__ ald,
                      const float* __restrict__ h, const float* __restrict__ bias,
                      float* __restrict__ out) {
    int wid = threadIdx.x >> 6, lane = threadIdx.x & 63;
    int n = blockIdx.x * 4 + wid;
    if (n >= NN) return;
    constexpr bool TWO = (HC == 128);
    const int hh0 = lane / C;
    const int hh1 = TWO ? (2 + lane / C) : 0;
    float aldd0 = ald[n * 4 + hh0];
    float ev_self0 = leaky(als[n * 4 + hh0] + aldd0);
    float mx0 = ev_self0;
    float aldd1 = 0.f, ev_self1 = 0.f, mx1 = 0.f;
    if (TWO) {
        aldd1 = ald[n * 4 + hh1];
        ev_self1 = leaky(als[n * 4 + hh1] + aldd1);
        mx1 = ev_self1;
    }
    int beg = rp[n * RR], end = rp[n * RR + RR];
    for (int k = beg; k < end; k++) {
        int s = srcs[k];
        mx0 = fmaxf(mx0, leaky(als[s * 4 + hh0] + aldd0));
        if (TWO) mx1 = fmaxf(mx1, leaky(als[s * 4 + hh1] + aldd1));
    }
    float z0 = expf(ev_self0 - mx0);
    float acc0 = z0 * h[(size_t)n * HC + lane];
    float z1 = 0.f, acc1 = 0.f;
    if (TWO) {
        z1 = expf(ev_self1 - mx1);
        acc1 = z1 * h[(size_t)n * HC + 64 + lane];
    }
    for (int k = beg; k < end; k++) {
        int s = srcs[k];
        float p0 = expf(leaky(als[s * 4 + hh0] + aldd0) - mx0);
        z0 += p0;
        acc0 += p0 * h[(size_t)s * HC + lane];
        if (TWO) {
            float p1 = expf(leaky(als[s * 4 + hh1] + aldd1) - mx1);
            z1 += p1;
            acc1 += p1 * h[(size_t)s * HC + 64 + lane];
        }
    }
    if (!MEANOUT) {
        out[(size_t)n * HC + lane] = acc0 / z0 + bias[lane];
        if (TWO) out[(size_t)n * HC + 64 + lane] = acc1 / z1 + bias[64 + lane];
    } else {
        float v = acc0 / z0;  // lane = hh*16 + c; sum the 4 heads per channel
        v += __shfl_xor(v, 16);
        v += __shfl_xor(v, 32);
        if (lane < 16) {
            float o2 = 0.25f * v + bias[lane];
            o2 = fmaxf(o2, 0.f);
            out[n * 16 + lane] = tanhf(o2);
        }
    }
}

extern "C" void kernel_launch(void* const* d_in, const int* in_sizes, int n_in,
                              void* d_out, int out_size, void* d_ws, size_t ws_size,
                              hipStream_t stream) {
    const float* x      = (const float*)d_in[0];
    const int*   ei     = (const int*)d_in[1];
    const int*   et     = (const int*)d_in[2];
    const float* basis1 = (const float*)d_in[3];
    const float* comp1  = (const float*)d_in[4];
    const float* root1  = (const float*)d_in[5];
    const float* brg1   = (const float*)d_in[6];
    const float* wg1    = (const float*)d_in[7];
    const float* asrc1  = (const float*)d_in[8];
    const float* adst1  = (const float*)d_in[9];
    const float* bg1    = (const float*)d_in[10];
    const float* basis2 = (const float*)d_in[11];
    const float* comp2  = (const float*)d_in[12];
    const float* root2  = (const float*)d_in[13];
    const float* brg2   = (const float*)d_in[14];
    const float* wg2    = (const float*)d_in[15];
    const float* asrc2  = (const float*)d_in[16];
    const float* adst2  = (const float*)d_in[17];
    const float* bg2    = (const float*)d_in[18];
    const int* src = ei;
    const int* dst = ei + EE;
    float* out = (float*)d_out;

    // ---- workspace layout ----
    int* wsi = (int*)d_ws;
    size_t ioff = 0;
    auto ialloc = [&](size_t n) { int* p = wsi + ioff; ioff += (n + 3) & ~(size_t)3; return p; };
    int* cnt2 = ialloc(SEGS);       // zeroed per launch
    int* rp   = ialloc(SEGS + 1);   // row_ptr
    int* wo   = ialloc(SEGS + 1);   // bump-allocator cursors
    int* bsum = ialloc(2048);
    int* srcs = ialloc(EE);         // dst-major, relation-minor sorted src ids
    float* wsf = (float*)(wsi + ioff);
    size_t foff = 0;
    auto falloc = [&](size_t n) { float* p = wsf + foff; foff += (n + 3) & ~(size_t)3; return p; };
    float* mean = falloc((size_t)NN * 128);  // per-relation mean; reused as h1 in GAT1
    float* x1   = falloc((size_t)NN * 64);
    float* x2   = falloc((size_t)NN * 128);
    float* x3   = falloc((size_t)NN * 32);
    float* h2   = falloc((size_t)NN * 64);
    float* als  = falloc((size_t)NN * 4);    // reused for layer 2 and 4
    float* ald  = falloc((size_t)NN * 4);
    float* h1 = mean;                         // alias: mean dead during GAT1, h1 dead before L3
    if (ws_size < (ioff * sizeof(int) + foff * sizeof(float))) return;

    const int EB = (EE + 255) / 256;
    const int NB4 = (NN + 3) / 4;  // wave-per-node kernels
    const int GB = 2048;           // gemm grid

    // ---- CSR build (dst,relation)-sorted ----
    hipMemsetAsync(cnt2, 0, SEGS * sizeof(int), stream);
    k_count2<<<EB, 256, 0, stream>>>(dst, et, cnt2);
    k_scanA<<<NBLK, 256, 0, stream>>>(cnt2, rp, bsum);
    k_scanB<<<1, 256, 0, stream>>>(bsum);
    k_scanC<<<NBLK, 256, 0, stream>>>(rp, bsum, wo);
    k_fill<<<EB, 256, 0, stream>>>(src, dst, et, wo, srcs);

    // ---- layer 1: RGCN(64->64) + relu ----
    for (int r = 0; r < RR; r++) {
        k_gather<64><<<NB4, 256, 0, stream>>>(rp, srcs, x, r, mean);
        k_gemm<64, 64><<<GB, 256, 0, stream>>>(mean, nullptr, basis1, comp1, r,
                                               nullptr, x1, r > 0, 0);
    }
    k_gemm<64, 64><<<GB, 256, 0, stream>>>(x, root1, nullptr, nullptr, 0, brg1, x1, 1, 1);

    // ---- layer 2: GAT(64 -> 4x32 concat) ----
    k_gemm<64, 128><<<GB, 256, 0, stream>>>(x1, wg1, nullptr, nullptr, 0, nullptr, h1, 0, 0);
    k_gat_al<<<(NN * 4 + 255) / 256, 256, 0, stream>>>(h1, asrc1, adst1, als, ald, 32);
    k_gat<128, 32, false><<<NB4, 256, 0, stream>>>(rp, srcs, als, ald, h1, bg1, x2);

    // ---- layer 3: RGCN(128->32) + relu ----
    for (int r = 0; r < RR; r++) {
        k_gather<128><<<NB4, 256, 0, stream>>>(rp, srcs, x2, r, mean);
        k_gemm<128, 32><<<GB, 256, 0, stream>>>(mean, nullptr, basis2, comp2, r,
                                                nullptr, x3, r > 0, 0);
    }
    k_gemm<128, 32><<<GB, 256, 0, stream>>>(x2, root2, nullptr, nullptr, 0, brg2, x3, 1, 1);

    // ---- layer 4: GAT(32 -> 4x16, mean heads) + relu + tanh ----
    k_gemm<32, 64><<<GB, 256, 0, stream>>>(x3, wg2, nullptr, nullptr, 0, nullptr, h2, 0, 0);
    k_gat_al<<<(NN * 4 + 255) / 256, 256, 0, stream>>>(h2, asrc2, adst2, als, ald, 16);
    k_gat<64, 16, true><<<NB4, 256, 0, stream>>>(rp, srcs, als, ald, h2, bg2, out);
}